// Round 1
// baseline (4929.659 us; speedup 1.0000x reference)
//
#include <hip/hip_runtime.h>
#include <math.h>

#define NN 20000
#define NE 320000
#define H 128
#define NH (NN * H)

__device__ __forceinline__ float lrelu(float x) { return x > 0.f ? x : 0.01f * x; }
__device__ __forceinline__ float eluf(float x)  { return x > 0.f ? x : expm1f(x); }
__device__ __forceinline__ float sigf(float x)  { return 1.f / (1.f + __expf(-x)); }
#define BN_S 0.99999500003749973f  /* 1/sqrt(1+1e-5) */

// ---------------- layer 0: node linears (din=2) ----------------
__global__ __launch_bounds__(256) void k_nodelin0(
        const float* __restrict__ nf,
        const float* __restrict__ wa, const float* __restrict__ ba,
        const float* __restrict__ wb, const float* __restrict__ bb,
        const float* __restrict__ wd, const float* __restrict__ bd,
        const float* __restrict__ we, const float* __restrict__ be,
        float* __restrict__ lin) {
    int idx = blockIdx.x * 256 + threadIdx.x;   // NN*H threads
    int n = idx >> 7, c = idx & 127;
    float x0 = nf[n * 2], x1 = nf[n * 2 + 1];
    lin[0 * NH + idx] = fmaf(x0, wa[c], fmaf(x1, wa[128 + c], ba[c]));
    lin[1 * NH + idx] = fmaf(x0, wb[c], fmaf(x1, wb[128 + c], bb[c]));
    lin[2 * NH + idx] = fmaf(x0, wd[c], fmaf(x1, wd[128 + c], bd[c]));
    lin[3 * NH + idx] = fmaf(x0, we[c], fmaf(x1, we[128 + c], be[c]));
}

// ---------------- layer 0: edge update (ef scalar -> H) ----------------
__global__ __launch_bounds__(256) void k_edge0(
        const float* __restrict__ ef,
        const float* __restrict__ cw, const float* __restrict__ cb,
        const int* __restrict__ src, const int* __restrict__ dst,
        const float* __restrict__ lin,
        float* __restrict__ num, float* __restrict__ den,
        const float* __restrict__ g, const float* __restrict__ bt,
        float* __restrict__ ebuf) {
    const int tid = threadIdx.x;
    const int e  = blockIdx.x * 8 + (tid >> 5);
    const int c0 = (tid & 31) * 4;
    const int s = src[e], d = dst[e];
    const float ev = ef[e];
    const float4 cw4 = *(const float4*)(cw + c0);
    const float4 cb4 = *(const float4*)(cb + c0);
    const float4 Dh  = *(const float4*)(lin + 2 * NH + s * H + c0);
    const float4 Eh  = *(const float4*)(lin + 3 * NH + d * H + c0);
    const float4 Bh  = *(const float4*)(lin + 1 * NH + s * H + c0);
    const float4 g4  = *(const float4*)(g + c0);
    const float4 bt4 = *(const float4*)(bt + c0);
    float e2[4] = { fmaf(ev, cw4.x, cb4.x) + Dh.x + Eh.x,
                    fmaf(ev, cw4.y, cb4.y) + Dh.y + Eh.y,
                    fmaf(ev, cw4.z, cb4.z) + Dh.z + Eh.z,
                    fmaf(ev, cw4.w, cb4.w) + Dh.w + Eh.w };
    const float bh[4] = { Bh.x, Bh.y, Bh.z, Bh.w };
    const float gg[4] = { g4.x, g4.y, g4.z, g4.w };
    const float bb[4] = { bt4.x, bt4.y, bt4.z, bt4.w };
    float o[4];
#pragma unroll
    for (int j = 0; j < 4; ++j) {
        float sg = sigf(e2[j]);
        atomicAdd(num + d * H + c0 + j, sg * bh[j]);
        atomicAdd(den + d * H + c0 + j, sg);
        float t = fmaf(gg[j], e2[j] * BN_S, bb[j]);
        o[j] = lrelu(eluf(t));   // elu inside conv, leaky outside; no residual
    }
    *(float4*)(ebuf + e * H + c0) = make_float4(o[0], o[1], o[2], o[3]);
}

// ---------------- node update (h2 = Ah + num/den, BN, act, [res], leaky) --
template <int ELU, int RES>
__global__ __launch_bounds__(256) void k_nodeupd(
        const float* __restrict__ lin,
        const float* __restrict__ num, const float* __restrict__ den,
        const float* __restrict__ g, const float* __restrict__ bt,
        const float* __restrict__ hin, float* __restrict__ hout) {
    int idx = blockIdx.x * 256 + threadIdx.x;   // NN*32 threads
    int n = idx >> 5, c0 = (idx & 31) * 4;
    int off = n * H + c0;
    const float4 Ah = *(const float4*)(lin + off);
    const float4 nu = *(const float4*)(num + off);
    const float4 de = *(const float4*)(den + off);
    const float4 g4 = *(const float4*)(g + c0);
    const float4 b4 = *(const float4*)(bt + c0);
    float a[4]  = { Ah.x, Ah.y, Ah.z, Ah.w };
    float nn_[4] = { nu.x, nu.y, nu.z, nu.w };
    float dd[4] = { de.x, de.y, de.z, de.w };
    float gg[4] = { g4.x, g4.y, g4.z, g4.w };
    float bb[4] = { b4.x, b4.y, b4.z, b4.w };
    float r4[4] = { 0.f, 0.f, 0.f, 0.f };
    if (RES) {
        const float4 hi = *(const float4*)(hin + off);
        r4[0] = hi.x; r4[1] = hi.y; r4[2] = hi.z; r4[3] = hi.w;
    }
    float o[4];
#pragma unroll
    for (int j = 0; j < 4; ++j) {
        float h2 = a[j] + nn_[j] / (dd[j] + 1e-6f);
        h2 = fmaf(gg[j], h2 * BN_S, bb[j]);
        h2 = ELU ? eluf(h2) : lrelu(h2);
        if (RES) h2 += r4[j];
        o[j] = lrelu(h2);
    }
    *(float4*)(hout + off) = make_float4(o[0], o[1], o[2], o[3]);
}

// ---------------- layers 1-2: node linears GEMM (N x 128 @ 128 x 128, x4) --
__global__ __launch_bounds__(256) void k_nodegemm(
        const float* __restrict__ h,
        const float* __restrict__ wa, const float* __restrict__ wb,
        const float* __restrict__ wd, const float* __restrict__ we,
        const float* __restrict__ ba, const float* __restrict__ bb,
        const float* __restrict__ bd, const float* __restrict__ be,
        float* __restrict__ lin) {
    __shared__ float AT[H][68];   // transposed tile, pad 4 -> b128-aligned rows
    const int tid = threadIdx.x;
    const int nbase = blockIdx.x * 64;
    const int which = blockIdx.y;
    const float* W = which == 0 ? wa : which == 1 ? wb : which == 2 ? wd : we;
    const float* B = which == 0 ? ba : which == 1 ? bb : which == 2 ? bd : be;
#pragma unroll
    for (int rep = 0; rep < 32; ++rep) {
        int idx = rep * 256 + tid;
        int k = idx & 127, r = idx >> 7;
        int n = nbase + r;
        AT[k][r] = (n < NN) ? h[n * H + k] : 0.f;
    }
    __syncthreads();
    const int tx = tid & 31, ty = tid >> 5, c0 = tx * 4;
    float acc[8][4] = {};
#pragma unroll 4
    for (int k = 0; k < H; ++k) {
        const float4 b = *(const float4*)(W + k * H + c0);  // L1/L2-resident
        const float4 alo = *(const float4*)(&AT[k][ty * 8]);
        const float4 ahi = *(const float4*)(&AT[k][ty * 8 + 4]);
        const float a[8] = { alo.x, alo.y, alo.z, alo.w, ahi.x, ahi.y, ahi.z, ahi.w };
#pragma unroll
        for (int r = 0; r < 8; ++r) {
            acc[r][0] = fmaf(a[r], b.x, acc[r][0]);
            acc[r][1] = fmaf(a[r], b.y, acc[r][1]);
            acc[r][2] = fmaf(a[r], b.z, acc[r][2]);
            acc[r][3] = fmaf(a[r], b.w, acc[r][3]);
        }
    }
    const float4 bias = *(const float4*)(B + c0);
#pragma unroll
    for (int r = 0; r < 8; ++r) {
        int n = nbase + ty * 8 + r;
        if (n < NN) {
            *(float4*)(lin + which * NH + n * H + c0) =
                make_float4(acc[r][0] + bias.x, acc[r][1] + bias.y,
                            acc[r][2] + bias.z, acc[r][3] + bias.w);
        }
    }
}

// ---------------- layers 1-2: fused edge kernel --------------------------
// e2 = e@Cw + Cb + Dh[src] + Eh[dst]; sig; atomic num/den; e = lrelu(lrelu(BN(e2)) + e_in)
__global__ __launch_bounds__(256) void k_edgegemm(
        float* __restrict__ ebuf, const float* __restrict__ W,
        const float* __restrict__ cb,
        const int* __restrict__ src, const int* __restrict__ dst,
        const float* __restrict__ lin,
        float* __restrict__ num, float* __restrict__ den,
        const float* __restrict__ g, const float* __restrict__ bt) {
    __shared__ float AT[H][68];
    const int tid = threadIdx.x;
    const int ebase = blockIdx.x * 64;
#pragma unroll
    for (int rep = 0; rep < 32; ++rep) {
        int idx = rep * 256 + tid;
        int k = idx & 127, r = idx >> 7;
        AT[k][r] = ebuf[(ebase + r) * H + k];
    }
    __syncthreads();
    const int tx = tid & 31, ty = tid >> 5, c0 = tx * 4;
    float acc[8][4] = {};
#pragma unroll 4
    for (int k = 0; k < H; ++k) {
        const float4 b = *(const float4*)(W + k * H + c0);
        const float4 alo = *(const float4*)(&AT[k][ty * 8]);
        const float4 ahi = *(const float4*)(&AT[k][ty * 8 + 4]);
        const float a[8] = { alo.x, alo.y, alo.z, alo.w, ahi.x, ahi.y, ahi.z, ahi.w };
#pragma unroll
        for (int r = 0; r < 8; ++r) {
            acc[r][0] = fmaf(a[r], b.x, acc[r][0]);
            acc[r][1] = fmaf(a[r], b.y, acc[r][1]);
            acc[r][2] = fmaf(a[r], b.z, acc[r][2]);
            acc[r][3] = fmaf(a[r], b.w, acc[r][3]);
        }
    }
    const float4 cb4 = *(const float4*)(cb + c0);
    const float4 g4  = *(const float4*)(g + c0);
    const float4 bt4 = *(const float4*)(bt + c0);
    const float cbv[4] = { cb4.x, cb4.y, cb4.z, cb4.w };
    const float gg[4]  = { g4.x, g4.y, g4.z, g4.w };
    const float bb[4]  = { bt4.x, bt4.y, bt4.z, bt4.w };
#pragma unroll
    for (int r = 0; r < 8; ++r) {
        const int e = ebase + ty * 8 + r;
        const int s = src[e], d = dst[e];
        const float4 Dh = *(const float4*)(lin + 2 * NH + s * H + c0);
        const float4 Eh = *(const float4*)(lin + 3 * NH + d * H + c0);
        const float4 Bh = *(const float4*)(lin + 1 * NH + s * H + c0);
        float e2[4] = { acc[r][0] + cbv[0] + Dh.x + Eh.x,
                        acc[r][1] + cbv[1] + Dh.y + Eh.y,
                        acc[r][2] + cbv[2] + Dh.z + Eh.z,
                        acc[r][3] + cbv[3] + Dh.w + Eh.w };
        const float bh[4] = { Bh.x, Bh.y, Bh.z, Bh.w };
        float o[4];
#pragma unroll
        for (int j = 0; j < 4; ++j) {
            float sg = sigf(e2[j]);
            atomicAdd(num + d * H + c0 + j, sg * bh[j]);
            atomicAdd(den + d * H + c0 + j, sg);
            float t = fmaf(gg[j], e2[j] * BN_S, bb[j]);
            t = lrelu(t);                 // act inside conv
            t += AT[c0 + j][ty * 8 + r];  // residual e_in (from LDS; in-place safe)
            o[j] = lrelu(t);              // outer leaky
        }
        *(float4*)(ebuf + e * H + c0) = make_float4(o[0], o[1], o[2], o[3]);
    }
}

// ---------------- final edge MLP: concat[h_src,h_dst,e] @ w1, relu, @ w2 --
__global__ __launch_bounds__(256) void k_mlp(
        const float* __restrict__ h, const float* __restrict__ ebuf,
        const int* __restrict__ src, const int* __restrict__ dst,
        const float* __restrict__ w1, const float* __restrict__ b1,
        const float* __restrict__ w2, const float* __restrict__ b2,
        float* __restrict__ out) {
    __shared__ float AT[H][68];
    const int tid = threadIdx.x;
    const int ebase = blockIdx.x * 64;
    const int tx = tid & 31, ty = tid >> 5, c0 = tx * 4;
    float acc[8][4] = {};
    for (int chunk = 0; chunk < 3; ++chunk) {
#pragma unroll
        for (int rep = 0; rep < 32; ++rep) {
            int idx = rep * 256 + tid;
            int k = idx & 127, r = idx >> 7;
            int e = ebase + r;
            float v;
            if (chunk == 0)      v = h[src[e] * H + k];
            else if (chunk == 1) v = h[dst[e] * H + k];
            else                 v = ebuf[e * H + k];
            AT[k][r] = v;
        }
        __syncthreads();
        const float* Wc = w1 + chunk * H * H;
#pragma unroll 4
        for (int k = 0; k < H; ++k) {
            const float4 b = *(const float4*)(Wc + k * H + c0);
            const float4 alo = *(const float4*)(&AT[k][ty * 8]);
            const float4 ahi = *(const float4*)(&AT[k][ty * 8 + 4]);
            const float a[8] = { alo.x, alo.y, alo.z, alo.w, ahi.x, ahi.y, ahi.z, ahi.w };
#pragma unroll
            for (int r = 0; r < 8; ++r) {
                acc[r][0] = fmaf(a[r], b.x, acc[r][0]);
                acc[r][1] = fmaf(a[r], b.y, acc[r][1]);
                acc[r][2] = fmaf(a[r], b.z, acc[r][2]);
                acc[r][3] = fmaf(a[r], b.w, acc[r][3]);
            }
        }
        __syncthreads();
    }
    const float4 b1v = *(const float4*)(b1 + c0);
    const float bb1[4] = { b1v.x, b1v.y, b1v.z, b1v.w };
    float w20[4], w21[4];
#pragma unroll
    for (int j = 0; j < 4; ++j) {
        w20[j] = w2[(c0 + j) * 2];
        w21[j] = w2[(c0 + j) * 2 + 1];
    }
    const float b2v0 = b2[0], b2v1 = b2[1];
#pragma unroll
    for (int r = 0; r < 8; ++r) {
        float p0 = 0.f, p1 = 0.f;
#pragma unroll
        for (int j = 0; j < 4; ++j) {
            float hv = fmaxf(acc[r][j] + bb1[j], 0.f);
            p0 = fmaf(hv, w20[j], p0);
            p1 = fmaf(hv, w21[j], p1);
        }
#pragma unroll
        for (int off = 16; off > 0; off >>= 1) {
            p0 += __shfl_down(p0, off, 32);
            p1 += __shfl_down(p1, off, 32);
        }
        if (tx == 0) {
            int e = ebase + ty * 8 + r;
            out[e * 2]     = p0 + b2v0;
            out[e * 2 + 1] = p1 + b2v1;
        }
    }
}

extern "C" void kernel_launch(void* const* d_in, const int* in_sizes, int n_in,
                              void* d_out, int out_size, void* d_ws, size_t ws_size,
                              hipStream_t stream) {
    const float* nf  = (const float*)d_in[0];
    const float* ef  = (const float*)d_in[1];
    const int*   src = (const int*)d_in[2];
    const int*   dst = (const int*)d_in[3];
    const float *a0w = (const float*)d_in[4],  *a0b = (const float*)d_in[5];
    const float *b0w = (const float*)d_in[6],  *b0b = (const float*)d_in[7];
    const float *c0w = (const float*)d_in[8],  *c0b = (const float*)d_in[9];
    const float *d0w = (const float*)d_in[10], *d0b = (const float*)d_in[11];
    const float *e0w = (const float*)d_in[12], *e0b = (const float*)d_in[13];
    const float *bnh0g = (const float*)d_in[14], *bnh0b = (const float*)d_in[15];
    const float *bne0g = (const float*)d_in[16], *bne0b = (const float*)d_in[17];
    const float *aLw = (const float*)d_in[18], *aLb = (const float*)d_in[19];
    const float *bLw = (const float*)d_in[20], *bLb = (const float*)d_in[21];
    const float *cLw = (const float*)d_in[22], *cLb = (const float*)d_in[23];
    const float *dLw = (const float*)d_in[24], *dLb = (const float*)d_in[25];
    const float *eLw = (const float*)d_in[26], *eLb = (const float*)d_in[27];
    const float *bnhLg = (const float*)d_in[28], *bnhLb = (const float*)d_in[29];
    const float *bneLg = (const float*)d_in[30], *bneLb = (const float*)d_in[31];
    const float *w1 = (const float*)d_in[32], *b1 = (const float*)d_in[33];
    const float *w2 = (const float*)d_in[34], *b2 = (const float*)d_in[35];
    float* out = (float*)d_out;

    // workspace layout (floats): ebuf[NE*H] | lin[4*NH] | num[NH] den[NH] | h0[NH] | h1[NH]
    float* ws   = (float*)d_ws;
    float* ebuf = ws;
    float* lin  = ebuf + (size_t)NE * H;
    float* numd = lin + 4ull * NH;
    float* h0   = numd + 2ull * NH;
    float* h1   = h0 + NH;
    float* num = numd;
    float* den = numd + NH;

    // ---- layer 0 ----
    k_nodelin0<<<NN * H / 256, 256, 0, stream>>>(nf, a0w, a0b, b0w, b0b, d0w, d0b, e0w, e0b, lin);
    hipMemsetAsync(numd, 0, 2ull * NH * sizeof(float), stream);
    k_edge0<<<NE / 8, 256, 0, stream>>>(ef, c0w, c0b, src, dst, lin, num, den, bne0g, bne0b, ebuf);
    k_nodeupd<1, 0><<<NN * 32 / 256, 256, 0, stream>>>(lin, num, den, bnh0g, bnh0b, nullptr, h0);

    // ---- layers 1..2 ----
    for (int l = 0; l < 2; ++l) {
        const float* hin = (l == 0) ? h0 : h1;
        float* hout      = (l == 0) ? h1 : h0;
        const size_t HH = (size_t)H * H;
        k_nodegemm<<<dim3(313, 4), 256, 0, stream>>>(hin,
            aLw + l * HH, bLw + l * HH, dLw + l * HH, eLw + l * HH,
            aLb + l * H,  bLb + l * H,  dLb + l * H,  eLb + l * H, lin);
        hipMemsetAsync(numd, 0, 2ull * NH * sizeof(float), stream);
        k_edgegemm<<<NE / 64, 256, 0, stream>>>(ebuf, cLw + l * HH, cLb + l * H,
                                                src, dst, lin, num, den,
                                                bneLg + l * H, bneLb + l * H);
        k_nodeupd<0, 1><<<NN * 32 / 256, 256, 0, stream>>>(lin, num, den,
                                                           bnhLg + l * H, bnhLb + l * H,
                                                           hin, hout);
    }

    // ---- edge classifier MLP ----  (final h is in h0 after l=1)
    k_mlp<<<NE / 64, 256, 0, stream>>>(h0, ebuf, src, dst, w1, b1, w2, b2, out);

    (void)in_sizes; (void)n_in; (void)out_size; (void)ws_size;
}

// Round 2
// 1964.121 us; speedup vs baseline: 2.5099x; 2.5099x over previous
//
#include <hip/hip_runtime.h>
#include <hip/hip_bf16.h>
#include <math.h>

#define NN 20000
#define NE 320000
#define H 128
#define NH (NN * H)

typedef short bf16x8 __attribute__((ext_vector_type(8)));
typedef float f32x4 __attribute__((ext_vector_type(4)));

__device__ __forceinline__ float lrelu(float x) { return x > 0.f ? x : 0.01f * x; }
__device__ __forceinline__ float eluf(float x)  { return x > 0.f ? x : expm1f(x); }
__device__ __forceinline__ float sigf(float x)  { return 1.f / (1.f + __expf(-x)); }
__device__ __forceinline__ unsigned short f2b(float x) {
    __hip_bfloat16 h = __float2bfloat16(x);
    return *reinterpret_cast<unsigned short*>(&h);
}
#define BN_S 0.99999500003749973f  /* 1/sqrt(1+1e-5) */

// ---------------- weight pre-pack into MFMA B-fragment order --------------
// B-frag for 16x16x32: lane holds B[k=quad*8+j][n=tile*16+(lane&15)], j=0..7
// pack[m][((t*4+kk)*64+lane)*8+j] = bf16(W[kk*32+quad*8+j][t*16+(lane&15)])
struct PackPtrs { const float* w[13]; };
__global__ __launch_bounds__(256) void k_pack(PackPtrs p, unsigned short* __restrict__ dst) {
    int gid = blockIdx.x * 256 + threadIdx.x;   // 13 * 2048 threads
    int m = gid >> 11;
    int r = gid & 2047;
    int t = r >> 8, kk = (r >> 6) & 3, lane = r & 63;
    const float* W = p.w[m];
    int col = t * 16 + (lane & 15);
    int krow = kk * 32 + (lane >> 4) * 8;
    unsigned short* o = dst + (size_t)m * 16384 + (size_t)r * 8;
#pragma unroll
    for (int j = 0; j < 8; ++j) o[j] = f2b(W[(krow + j) * H + col]);
}

// ---------------- layer 0: node linears (din=2) ----------------
__global__ __launch_bounds__(256) void k_nodelin0(
        const float* __restrict__ nf,
        const float* __restrict__ wa, const float* __restrict__ ba,
        const float* __restrict__ wb, const float* __restrict__ bb,
        const float* __restrict__ wd, const float* __restrict__ bd,
        const float* __restrict__ we, const float* __restrict__ be,
        float* __restrict__ lin) {
    int idx = blockIdx.x * 256 + threadIdx.x;
    int n = idx >> 7, c = idx & 127;
    float x0 = nf[n * 2], x1 = nf[n * 2 + 1];
    lin[0 * NH + idx] = fmaf(x0, wa[c], fmaf(x1, wa[128 + c], ba[c]));
    lin[1 * NH + idx] = fmaf(x0, wb[c], fmaf(x1, wb[128 + c], bb[c]));
    lin[2 * NH + idx] = fmaf(x0, wd[c], fmaf(x1, wd[128 + c], bd[c]));
    lin[3 * NH + idx] = fmaf(x0, we[c], fmaf(x1, we[128 + c], be[c]));
}

// ---------------- layer 0: edge update (ef scalar -> H) ----------------
__global__ __launch_bounds__(256) void k_edge0(
        const float* __restrict__ ef,
        const float* __restrict__ cw, const float* __restrict__ cb,
        const int* __restrict__ src, const int* __restrict__ dst,
        const float* __restrict__ lin,
        float* __restrict__ num, float* __restrict__ den,
        const float* __restrict__ g, const float* __restrict__ bt,
        float* __restrict__ ebuf) {
    const int tid = threadIdx.x;
    const int e  = blockIdx.x * 8 + (tid >> 5);
    const int c0 = (tid & 31) * 4;
    const int s = src[e], d = dst[e];
    const float ev = ef[e];
    const float4 cw4 = *(const float4*)(cw + c0);
    const float4 cb4 = *(const float4*)(cb + c0);
    const float4 Dh  = *(const float4*)(lin + 2 * NH + s * H + c0);
    const float4 Eh  = *(const float4*)(lin + 3 * NH + d * H + c0);
    const float4 Bh  = *(const float4*)(lin + 1 * NH + s * H + c0);
    const float4 g4  = *(const float4*)(g + c0);
    const float4 bt4 = *(const float4*)(bt + c0);
    float e2[4] = { fmaf(ev, cw4.x, cb4.x) + Dh.x + Eh.x,
                    fmaf(ev, cw4.y, cb4.y) + Dh.y + Eh.y,
                    fmaf(ev, cw4.z, cb4.z) + Dh.z + Eh.z,
                    fmaf(ev, cw4.w, cb4.w) + Dh.w + Eh.w };
    const float bh[4] = { Bh.x, Bh.y, Bh.z, Bh.w };
    const float gg[4] = { g4.x, g4.y, g4.z, g4.w };
    const float bb[4] = { bt4.x, bt4.y, bt4.z, bt4.w };
    float o[4];
#pragma unroll
    for (int j = 0; j < 4; ++j) {
        float sg = sigf(e2[j]);
        atomicAdd(num + d * H + c0 + j, sg * bh[j]);
        atomicAdd(den + d * H + c0 + j, sg);
        float t = fmaf(gg[j], e2[j] * BN_S, bb[j]);
        o[j] = lrelu(eluf(t));
    }
    *(float4*)(ebuf + (size_t)e * H + c0) = make_float4(o[0], o[1], o[2], o[3]);
}

// ---------------- node update ----------------
template <int ELU, int RES>
__global__ __launch_bounds__(256) void k_nodeupd(
        const float* __restrict__ lin,
        const float* __restrict__ num, const float* __restrict__ den,
        const float* __restrict__ g, const float* __restrict__ bt,
        const float* __restrict__ hin, float* __restrict__ hout) {
    int idx = blockIdx.x * 256 + threadIdx.x;
    int n = idx >> 5, c0 = (idx & 31) * 4;
    int off = n * H + c0;
    const float4 Ah = *(const float4*)(lin + off);
    const float4 nu = *(const float4*)(num + off);
    const float4 de = *(const float4*)(den + off);
    const float4 g4 = *(const float4*)(g + c0);
    const float4 b4 = *(const float4*)(bt + c0);
    float a[4]  = { Ah.x, Ah.y, Ah.z, Ah.w };
    float nn_[4] = { nu.x, nu.y, nu.z, nu.w };
    float dd[4] = { de.x, de.y, de.z, de.w };
    float gg[4] = { g4.x, g4.y, g4.z, g4.w };
    float bb[4] = { b4.x, b4.y, b4.z, b4.w };
    float r4[4] = { 0.f, 0.f, 0.f, 0.f };
    if (RES) {
        const float4 hi = *(const float4*)(hin + off);
        r4[0] = hi.x; r4[1] = hi.y; r4[2] = hi.z; r4[3] = hi.w;
    }
    float o[4];
#pragma unroll
    for (int j = 0; j < 4; ++j) {
        float h2 = a[j] + nn_[j] / (dd[j] + 1e-6f);
        h2 = fmaf(gg[j], h2 * BN_S, bb[j]);
        h2 = ELU ? eluf(h2) : lrelu(h2);
        if (RES) h2 += r4[j];
        o[j] = lrelu(h2);
    }
    *(float4*)(hout + off) = make_float4(o[0], o[1], o[2], o[3]);
}

// ---------------- MFMA node GEMM: lin[which] = h @ W_which + b ------------
__global__ __launch_bounds__(256) void k_nodegemm(
        const float* __restrict__ h,
        const unsigned short* __restrict__ wpack,   // base of this layer's a,b,d,e packs
        const float* __restrict__ ba, const float* __restrict__ bb,
        const float* __restrict__ bd, const float* __restrict__ be,
        float* __restrict__ lin) {
    __shared__ __align__(16) unsigned short AT[64][136];
    const int tid = threadIdx.x;
    const int nbase = blockIdx.x * 64;
    const int which = blockIdx.y;
    const unsigned short* Wp = wpack + (size_t)which * 16384;
    const float* B = which == 0 ? ba : which == 1 ? bb : which == 2 ? bd : be;
#pragma unroll
    for (int rep = 0; rep < 8; ++rep) {
        int flat = (rep * 256 + tid) * 4;
        int r = flat >> 7, k0 = flat & 127;
        int n = nbase + r;
        float4 v = make_float4(0.f, 0.f, 0.f, 0.f);
        if (n < NN) v = *(const float4*)(h + (size_t)n * H + k0);
        ushort4 u = { f2b(v.x), f2b(v.y), f2b(v.z), f2b(v.w) };
        *(ushort4*)(&AT[r][k0]) = u;
    }
    __syncthreads();
    const int lane = tid & 63, wave = tid >> 6;
    const int lrow = lane & 15, quad = lane >> 4;
    f32x4 acc[8] = {};
#pragma unroll
    for (int kk = 0; kk < 4; ++kk) {
        bf16x8 af = *(const bf16x8*)(&AT[wave * 16 + lrow][kk * 32 + quad * 8]);
#pragma unroll
        for (int t = 0; t < 8; ++t) {
            bf16x8 bfv = *(const bf16x8*)(Wp + ((t * 4 + kk) * 64 + lane) * 8);
            acc[t] = __builtin_amdgcn_mfma_f32_16x16x32_bf16(af, bfv, acc[t], 0, 0, 0);
        }
    }
#pragma unroll
    for (int t = 0; t < 8; ++t) {
        int col = t * 16 + lrow;
        float bv = B[col];
#pragma unroll
        for (int reg = 0; reg < 4; ++reg) {
            int n = nbase + wave * 16 + quad * 4 + reg;
            if (n < NN)
                lin[(size_t)which * NH + (size_t)n * H + col] = acc[t][reg] + bv;
        }
    }
}

// ---------------- MFMA fused edge kernel (layers 1-2) ---------------------
__global__ __launch_bounds__(256) void k_edgegemm(
        float* __restrict__ ebuf, const unsigned short* __restrict__ Wp,
        const float* __restrict__ cb,
        const int* __restrict__ src, const int* __restrict__ dst,
        const float* __restrict__ lin,
        float* __restrict__ num, float* __restrict__ den,
        const float* __restrict__ g, const float* __restrict__ bt) {
    __shared__ __align__(16) unsigned short AT[64][136];
    const int tid = threadIdx.x;
    const int ebase = blockIdx.x * 64;
#pragma unroll
    for (int rep = 0; rep < 8; ++rep) {
        int flat = (rep * 256 + tid) * 4;
        int r = flat >> 7, k0 = flat & 127;
        float4 v = *(const float4*)(ebuf + (size_t)(ebase + r) * H + k0);
        ushort4 u = { f2b(v.x), f2b(v.y), f2b(v.z), f2b(v.w) };
        *(ushort4*)(&AT[r][k0]) = u;
    }
    __syncthreads();
    const int lane = tid & 63, wave = tid >> 6;
    const int lrow = lane & 15, quad = lane >> 4;
    f32x4 acc[8] = {};
#pragma unroll
    for (int kk = 0; kk < 4; ++kk) {
        bf16x8 af = *(const bf16x8*)(&AT[wave * 16 + lrow][kk * 32 + quad * 8]);
#pragma unroll
        for (int t = 0; t < 8; ++t) {
            bf16x8 bfv = *(const bf16x8*)(Wp + ((t * 4 + kk) * 64 + lane) * 8);
            acc[t] = __builtin_amdgcn_mfma_f32_16x16x32_bf16(af, bfv, acc[t], 0, 0, 0);
        }
    }
    const int e0 = ebase + wave * 16 + quad * 4;
    int sv[4], dv[4];
#pragma unroll
    for (int reg = 0; reg < 4; ++reg) { sv[reg] = src[e0 + reg]; dv[reg] = dst[e0 + reg]; }
#pragma unroll
    for (int t = 0; t < 8; ++t) {
        int col = t * 16 + lrow;
        float cbv = cb[col], gv = g[col], btv = bt[col];
#pragma unroll
        for (int reg = 0; reg < 4; ++reg) {
            int s = sv[reg], d = dv[reg];
            float Dh  = lin[2 * NH + (size_t)s * H + col];
            float Eh  = lin[3 * NH + (size_t)d * H + col];
            float Bhv = lin[1 * NH + (size_t)s * H + col];
            float e2 = acc[t][reg] + cbv + Dh + Eh;
            float sg = sigf(e2);
            atomicAdd(num + (size_t)d * H + col, sg * Bhv);
            atomicAdd(den + (size_t)d * H + col, sg);
            float tt = lrelu(fmaf(gv, e2 * BN_S, btv));
            size_t eoff = (size_t)(e0 + reg) * H + col;
            float ein = ebuf[eoff];          // fp32 residual, L2-hot (just staged)
            ebuf[eoff] = lrelu(tt + ein);
        }
    }
}

// ---------------- MFMA edge MLP -------------------------------------------
__global__ __launch_bounds__(256) void k_mlp(
        const float* __restrict__ h, const float* __restrict__ ebuf,
        const int* __restrict__ src, const int* __restrict__ dst,
        const unsigned short* __restrict__ w1p,   // 3 chunk packs
        const float* __restrict__ b1,
        const float* __restrict__ w2, const float* __restrict__ b2,
        float* __restrict__ out) {
    __shared__ __align__(16) unsigned short AT[64][136];
    const int tid = threadIdx.x;
    const int ebase = blockIdx.x * 64;
    const int lane = tid & 63, wave = tid >> 6;
    const int lrow = lane & 15, quad = lane >> 4;
    f32x4 acc[8] = {};
    for (int chunk = 0; chunk < 3; ++chunk) {
#pragma unroll
        for (int rep = 0; rep < 8; ++rep) {
            int flat = (rep * 256 + tid) * 4;
            int r = flat >> 7, k0 = flat & 127;
            int e = ebase + r;
            const float* base = chunk == 0 ? h + (size_t)src[e] * H
                              : chunk == 1 ? h + (size_t)dst[e] * H
                                           : ebuf + (size_t)e * H;
            float4 v = *(const float4*)(base + k0);
            ushort4 u = { f2b(v.x), f2b(v.y), f2b(v.z), f2b(v.w) };
            *(ushort4*)(&AT[r][k0]) = u;
        }
        __syncthreads();
        const unsigned short* Wp = w1p + (size_t)chunk * 16384;
#pragma unroll
        for (int kk = 0; kk < 4; ++kk) {
            bf16x8 af = *(const bf16x8*)(&AT[wave * 16 + lrow][kk * 32 + quad * 8]);
#pragma unroll
            for (int t = 0; t < 8; ++t) {
                bf16x8 bfv = *(const bf16x8*)(Wp + ((t * 4 + kk) * 64 + lane) * 8);
                acc[t] = __builtin_amdgcn_mfma_f32_16x16x32_bf16(af, bfv, acc[t], 0, 0, 0);
            }
        }
        __syncthreads();
    }
    const float b20 = b2[0], b21 = b2[1];
#pragma unroll
    for (int reg = 0; reg < 4; ++reg) {
        float p0 = 0.f, p1 = 0.f;
#pragma unroll
        for (int t = 0; t < 8; ++t) {
            int col = t * 16 + lrow;
            float hv = fmaxf(acc[t][reg] + b1[col], 0.f);
            p0 = fmaf(hv, w2[col * 2], p0);
            p1 = fmaf(hv, w2[col * 2 + 1], p1);
        }
#pragma unroll
        for (int off = 8; off; off >>= 1) {
            p0 += __shfl_xor(p0, off, 16);
            p1 += __shfl_xor(p1, off, 16);
        }
        if (lrow == 0) {
            int e = ebase + wave * 16 + quad * 4 + reg;
            out[e * 2]     = p0 + b20;
            out[e * 2 + 1] = p1 + b21;
        }
    }
}

extern "C" void kernel_launch(void* const* d_in, const int* in_sizes, int n_in,
                              void* d_out, int out_size, void* d_ws, size_t ws_size,
                              hipStream_t stream) {
    const float* nf  = (const float*)d_in[0];
    const float* ef  = (const float*)d_in[1];
    const int*   src = (const int*)d_in[2];
    const int*   dst = (const int*)d_in[3];
    const float *a0w = (const float*)d_in[4],  *a0b = (const float*)d_in[5];
    const float *b0w = (const float*)d_in[6],  *b0b = (const float*)d_in[7];
    const float *c0w = (const float*)d_in[8],  *c0b = (const float*)d_in[9];
    const float *d0w = (const float*)d_in[10], *d0b = (const float*)d_in[11];
    const float *e0w = (const float*)d_in[12], *e0b = (const float*)d_in[13];
    const float *bnh0g = (const float*)d_in[14], *bnh0b = (const float*)d_in[15];
    const float *bne0g = (const float*)d_in[16], *bne0b = (const float*)d_in[17];
    const float *aLw = (const float*)d_in[18], *aLb = (const float*)d_in[19];
    const float *bLw = (const float*)d_in[20], *bLb = (const float*)d_in[21];
    const float *cLw = (const float*)d_in[22], *cLb = (const float*)d_in[23];
    const float *dLw = (const float*)d_in[24], *dLb = (const float*)d_in[25];
    const float *eLw = (const float*)d_in[26], *eLb = (const float*)d_in[27];
    const float *bnhLg = (const float*)d_in[28], *bnhLb = (const float*)d_in[29];
    const float *bneLg = (const float*)d_in[30], *bneLb = (const float*)d_in[31];
    const float *w1 = (const float*)d_in[32], *b1 = (const float*)d_in[33];
    const float *w2 = (const float*)d_in[34], *b2 = (const float*)d_in[35];
    float* out = (float*)d_out;

    // ws layout (floats): ebuf[NE*H] | lin[4*NH] | num,den[2*NH] | h0[NH] | h1[NH] | wpack
    float* ws   = (float*)d_ws;
    float* ebuf = ws;
    float* lin  = ebuf + (size_t)NE * H;
    float* numd = lin + 4ull * NH;
    float* h0   = numd + 2ull * NH;
    float* h1   = h0 + NH;
    unsigned short* wpack = (unsigned short*)(h1 + NH);
    float* num = numd;
    float* den = numd + NH;

    // pack weights into MFMA B-fragment order (13 matrices of 128x128)
    // idx: l*5 + {0:a,1:b,2:d,3:e,4:c} for l in {0,1}; 10..12: w1 chunks
    PackPtrs pp;
    const size_t HH = (size_t)H * H;
    for (int l = 0; l < 2; ++l) {
        pp.w[l * 5 + 0] = aLw + l * HH;
        pp.w[l * 5 + 1] = bLw + l * HH;
        pp.w[l * 5 + 2] = dLw + l * HH;
        pp.w[l * 5 + 3] = eLw + l * HH;
        pp.w[l * 5 + 4] = cLw + l * HH;
    }
    pp.w[10] = w1; pp.w[11] = w1 + HH; pp.w[12] = w1 + 2 * HH;
    k_pack<<<104, 256, 0, stream>>>(pp, wpack);

    // ---- layer 0 ----
    k_nodelin0<<<NN * H / 256, 256, 0, stream>>>(nf, a0w, a0b, b0w, b0b, d0w, d0b, e0w, e0b, lin);
    hipMemsetAsync(numd, 0, 2ull * NH * sizeof(float), stream);
    k_edge0<<<NE / 8, 256, 0, stream>>>(ef, c0w, c0b, src, dst, lin, num, den, bne0g, bne0b, ebuf);
    k_nodeupd<1, 0><<<NN * 32 / 256, 256, 0, stream>>>(lin, num, den, bnh0g, bnh0b, nullptr, h0);

    // ---- layers 1..2 ----
    for (int l = 0; l < 2; ++l) {
        const float* hin = (l == 0) ? h0 : h1;
        float* hout      = (l == 0) ? h1 : h0;
        k_nodegemm<<<dim3(313, 4), 256, 0, stream>>>(hin,
            wpack + (size_t)l * 5 * 16384,
            aLb + l * H, bLb + l * H, dLb + l * H, eLb + l * H, lin);
        hipMemsetAsync(numd, 0, 2ull * NH * sizeof(float), stream);
        k_edgegemm<<<NE / 64, 256, 0, stream>>>(ebuf, wpack + (size_t)(l * 5 + 4) * 16384,
                                                cLb + l * H, src, dst, lin, num, den,
                                                bneLg + l * H, bneLb + l * H);
        k_nodeupd<0, 1><<<NN * 32 / 256, 256, 0, stream>>>(lin, num, den,
                                                           bnhLg + l * H, bnhLb + l * H,
                                                           hin, hout);
    }

    // ---- edge classifier MLP ---- (final h is h0)
    k_mlp<<<NE / 64, 256, 0, stream>>>(h0, ebuf, src, dst, wpack + 10ull * 16384,
                                       b1, w2, b2, out);

    (void)in_sizes; (void)n_in; (void)out_size; (void)ws_size;
}

// Round 4
// 1175.578 us; speedup vs baseline: 4.1934x; 1.6708x over previous
//
#include <hip/hip_runtime.h>
#include <hip/hip_bf16.h>
#include <math.h>

#define NN 20000
#define NE 320000
#define H 128
#define NH (NN * H)

typedef short bf16x8 __attribute__((ext_vector_type(8)));
typedef float f32x4 __attribute__((ext_vector_type(4)));

__device__ __forceinline__ float lrelu(float x) { return x > 0.f ? x : 0.01f * x; }
__device__ __forceinline__ float eluf(float x)  { return x > 0.f ? x : expm1f(x); }
__device__ __forceinline__ float sigf(float x)  { return 1.f / (1.f + __expf(-x)); }
__device__ __forceinline__ unsigned short f2b(float x) {
    __hip_bfloat16 h = __float2bfloat16(x);
    return *reinterpret_cast<unsigned short*>(&h);
}
#define BN_S 0.99999500003749973f  /* 1/sqrt(1+1e-5) */

// ---------------- weight pre-pack into MFMA B-fragment order --------------
struct PackPtrs { const float* w[13]; };
__global__ __launch_bounds__(256) void k_pack(PackPtrs p, unsigned short* __restrict__ dst) {
    int gid = blockIdx.x * 256 + threadIdx.x;   // 13 * 2048 threads
    int m = gid >> 11;
    int r = gid & 2047;
    int t = r >> 8, kk = (r >> 6) & 3, lane = r & 63;
    const float* W = p.w[m];
    int col = t * 16 + (lane & 15);
    int krow = kk * 32 + (lane >> 4) * 8;
    unsigned short* o = dst + (size_t)m * 16384 + (size_t)r * 8;
#pragma unroll
    for (int j = 0; j < 8; ++j) o[j] = f2b(W[(krow + j) * H + col]);
}

// ---------------- CSR build: deg histogram, scan, fill --------------------
__global__ __launch_bounds__(256) void k_deg(const int* __restrict__ dst, int* __restrict__ deg) {
    int e = blockIdx.x * 256 + threadIdx.x;
    if (e < NE) atomicAdd(&deg[dst[e]], 1);
}

__global__ __launch_bounds__(256) void k_scan(const int* __restrict__ deg,
                                              int* __restrict__ off, int* __restrict__ cursor) {
    __shared__ int sums[256];
    const int t = threadIdx.x;
    const int per = (NN + 255) / 256;   // 79
    const int base = t * per;
    int s = 0;
    for (int i = 0; i < per; ++i) { int idx = base + i; if (idx < NN) s += deg[idx]; }
    sums[t] = s;
    __syncthreads();
    for (int d = 1; d < 256; d <<= 1) {
        int v = (t >= d) ? sums[t - d] : 0;
        __syncthreads();
        sums[t] += v;
        __syncthreads();
    }
    int run = (t == 0) ? 0 : sums[t - 1];
    for (int i = 0; i < per; ++i) {
        int idx = base + i;
        if (idx < NN) { off[idx] = run; cursor[idx] = run; run += deg[idx]; }
    }
}

__global__ __launch_bounds__(256) void k_fill(const int* __restrict__ dst,
                                              int* __restrict__ cursor, int* __restrict__ csr) {
    int e = blockIdx.x * 256 + threadIdx.x;
    if (e < NE) {
        int pos = atomicAdd(&cursor[dst[e]], 1);
        csr[pos] = e;
    }
}

// ---------------- layer 0: node linears (din=2) ----------------
__global__ __launch_bounds__(256) void k_nodelin0(
        const float* __restrict__ nf,
        const float* __restrict__ wa, const float* __restrict__ ba,
        const float* __restrict__ wb, const float* __restrict__ bb,
        const float* __restrict__ wd, const float* __restrict__ bd,
        const float* __restrict__ we, const float* __restrict__ be,
        float* __restrict__ lin) {
    int idx = blockIdx.x * 256 + threadIdx.x;
    int n = idx >> 7, c = idx & 127;
    float x0 = nf[n * 2], x1 = nf[n * 2 + 1];
    lin[0 * NH + idx] = fmaf(x0, wa[c], fmaf(x1, wa[128 + c], ba[c]));
    lin[1 * NH + idx] = fmaf(x0, wb[c], fmaf(x1, wb[128 + c], bb[c]));
    lin[2 * NH + idx] = fmaf(x0, wd[c], fmaf(x1, wd[128 + c], bd[c]));
    lin[3 * NH + idx] = fmaf(x0, we[c], fmaf(x1, we[128 + c], be[c]));
}

// ---------------- layer 0: edge output only (no atomics) ------------------
__global__ __launch_bounds__(256) void k_edge0(
        const float* __restrict__ ef,
        const float* __restrict__ cw, const float* __restrict__ cb,
        const int* __restrict__ src, const int* __restrict__ dst,
        const float* __restrict__ lin,
        const float* __restrict__ g, const float* __restrict__ bt,
        float* __restrict__ ebuf) {
    const int tid = threadIdx.x;
    const int e  = blockIdx.x * 8 + (tid >> 5);
    const int c0 = (tid & 31) * 4;
    const int s = src[e], d = dst[e];
    const float ev = ef[e];
    const float4 cw4 = *(const float4*)(cw + c0);
    const float4 cb4 = *(const float4*)(cb + c0);
    const float4 Dh  = *(const float4*)(lin + 2 * NH + (size_t)s * H + c0);
    const float4 Eh  = *(const float4*)(lin + 3 * NH + (size_t)d * H + c0);
    const float4 g4  = *(const float4*)(g + c0);
    const float4 bt4 = *(const float4*)(bt + c0);
    float e2[4] = { fmaf(ev, cw4.x, cb4.x) + Dh.x + Eh.x,
                    fmaf(ev, cw4.y, cb4.y) + Dh.y + Eh.y,
                    fmaf(ev, cw4.z, cb4.z) + Dh.z + Eh.z,
                    fmaf(ev, cw4.w, cb4.w) + Dh.w + Eh.w };
    const float gg[4] = { g4.x, g4.y, g4.z, g4.w };
    const float bb[4] = { bt4.x, bt4.y, bt4.z, bt4.w };
    float o[4];
#pragma unroll
    for (int j = 0; j < 4; ++j) {
        float t = fmaf(gg[j], e2[j] * BN_S, bb[j]);
        o[j] = lrelu(eluf(t));
    }
    *(float4*)(ebuf + (size_t)e * H + c0) = make_float4(o[0], o[1], o[2], o[3]);
}

// ------- layer 0: fused aggregation + node update (pull, no atomics) ------
__global__ __launch_bounds__(256) void k_agg0(
        const int* __restrict__ csr, const int* __restrict__ off, const int* __restrict__ deg,
        const int* __restrict__ src,
        const float* __restrict__ ef, const float* __restrict__ cw, const float* __restrict__ cb,
        const float* __restrict__ lin,
        const float* __restrict__ g, const float* __restrict__ bt,
        float* __restrict__ hout) {
    const int tid = threadIdx.x;
    const int n = blockIdx.x * 2 + (tid >> 7);
    const int c = tid & 127;
    const int base = off[n], dg = deg[n];
    float num = 0.f, den = 0.f;
    const float Ehn = lin[3 * NH + (size_t)n * H + c];
    const float cwc = cw[c], cbc = cb[c];
    for (int i = 0; i < dg; ++i) {
        int eid = csr[base + i];
        int s = src[eid];
        float e2 = fmaf(ef[eid], cwc, cbc) + lin[2 * NH + (size_t)s * H + c] + Ehn;
        float sg = sigf(e2);
        num = fmaf(sg, lin[1 * NH + (size_t)s * H + c], num);
        den += sg;
    }
    float h2 = lin[(size_t)n * H + c] + num / (den + 1e-6f);
    h2 = fmaf(g[c], h2 * BN_S, bt[c]);
    h2 = eluf(h2);
    hout[(size_t)n * H + c] = lrelu(h2);
}

// ---------------- node update from numden (layers 1-2) --------------------
__global__ __launch_bounds__(256) void k_nodeupd(
        const float* __restrict__ lin, const float* __restrict__ numden,
        const float* __restrict__ g, const float* __restrict__ bt,
        const float* __restrict__ hin, float* __restrict__ hout) {
    int idx = blockIdx.x * 256 + threadIdx.x;   // NN*32 threads
    int n = idx >> 5, c0 = (idx & 31) * 4;
    int offh = n * H + c0;
    const float4 Ah  = *(const float4*)(lin + offh);
    const float4 nd0 = *(const float4*)(numden + (size_t)n * 256 + c0 * 2);      // n0,d0,n1,d1
    const float4 nd1 = *(const float4*)(numden + (size_t)n * 256 + c0 * 2 + 4);  // n2,d2,n3,d3
    const float4 g4 = *(const float4*)(g + c0);
    const float4 b4 = *(const float4*)(bt + c0);
    const float4 hi = *(const float4*)(hin + offh);
    float a[4]  = { Ah.x, Ah.y, Ah.z, Ah.w };
    float nu[4] = { nd0.x, nd0.z, nd1.x, nd1.z };
    float de[4] = { nd0.y, nd0.w, nd1.y, nd1.w };
    float gg[4] = { g4.x, g4.y, g4.z, g4.w };
    float bb[4] = { b4.x, b4.y, b4.z, b4.w };
    float r4[4] = { hi.x, hi.y, hi.z, hi.w };
    float o[4];
#pragma unroll
    for (int j = 0; j < 4; ++j) {
        float h2 = a[j] + nu[j] / (de[j] + 1e-6f);
        h2 = fmaf(gg[j], h2 * BN_S, bb[j]);
        h2 = lrelu(h2);
        h2 += r4[j];
        o[j] = lrelu(h2);
    }
    *(float4*)(hout + offh) = make_float4(o[0], o[1], o[2], o[3]);
}

// ---------------- MFMA node GEMM: lin[which] = h @ W_which + b ------------
__global__ __launch_bounds__(256) void k_nodegemm(
        const float* __restrict__ h,
        const unsigned short* __restrict__ wpack,
        const float* __restrict__ ba, const float* __restrict__ bb,
        const float* __restrict__ bd, const float* __restrict__ be,
        float* __restrict__ lin) {
    __shared__ __align__(16) unsigned short AT[64][136];
    const int tid = threadIdx.x;
    const int nbase = blockIdx.x * 64;
    const int which = blockIdx.y;
    const unsigned short* Wp = wpack + (size_t)which * 16384;
    const float* B = which == 0 ? ba : which == 1 ? bb : which == 2 ? bd : be;
#pragma unroll
    for (int rep = 0; rep < 8; ++rep) {
        int flat = (rep * 256 + tid) * 4;
        int r = flat >> 7, k0 = flat & 127;
        int n = nbase + r;
        float4 v = make_float4(0.f, 0.f, 0.f, 0.f);
        if (n < NN) v = *(const float4*)(h + (size_t)n * H + k0);
        ushort4 u = { f2b(v.x), f2b(v.y), f2b(v.z), f2b(v.w) };
        *(ushort4*)(&AT[r][k0]) = u;
    }
    __syncthreads();
    const int lane = tid & 63, wave = tid >> 6;
    const int lrow = lane & 15, quad = lane >> 4;
    f32x4 acc[8] = {};
#pragma unroll
    for (int kk = 0; kk < 4; ++kk) {
        bf16x8 af = *(const bf16x8*)(&AT[wave * 16 + lrow][kk * 32 + quad * 8]);
#pragma unroll
        for (int t = 0; t < 8; ++t) {
            bf16x8 bfv = *(const bf16x8*)(Wp + ((t * 4 + kk) * 64 + lane) * 8);
            acc[t] = __builtin_amdgcn_mfma_f32_16x16x32_bf16(af, bfv, acc[t], 0, 0, 0);
        }
    }
#pragma unroll
    for (int t = 0; t < 8; ++t) {
        int col = t * 16 + lrow;
        float bv = B[col];
#pragma unroll
        for (int reg = 0; reg < 4; ++reg) {
            int n = nbase + wave * 16 + quad * 4 + reg;
            if (n < NN)
                lin[(size_t)which * NH + (size_t)n * H + col] = acc[t][reg] + bv;
        }
    }
}

// ---- MFMA fused edge kernel (layers 1-2), dst-sorted rows ----------------
// rows are csr[ebase..ebase+63] (sorted by dst): segmented num/den reduction
// with boundary atomics into interleaved numden[n*256 + col*2 {+0,+1}].
__global__ __launch_bounds__(256) void k_edgegemm(
        float* __restrict__ ebuf,
        const unsigned short* __restrict__ Wp,
        const float* __restrict__ cb,
        const int* __restrict__ src, const int* __restrict__ dstv,
        const int* __restrict__ csr,
        const float* __restrict__ lin,
        float* __restrict__ numden,
        const float* __restrict__ g, const float* __restrict__ bt) {
    __shared__ __align__(16) unsigned short AT[64][136];
    const int tid = threadIdx.x;
    const int ebase = blockIdx.x * 64;
#pragma unroll
    for (int rep = 0; rep < 8; ++rep) {
        int flat = (rep * 256 + tid) * 4;
        int r = flat >> 7, k0 = flat & 127;
        int eid = csr[ebase + r];
        float4 v = *(const float4*)(ebuf + (size_t)eid * H + k0);
        ushort4 u = { f2b(v.x), f2b(v.y), f2b(v.z), f2b(v.w) };
        *(ushort4*)(&AT[r][k0]) = u;
    }
    __syncthreads();
    const int lane = tid & 63, wave = tid >> 6;
    const int lrow = lane & 15, quad = lane >> 4;
    f32x4 acc[8] = {};
#pragma unroll
    for (int kk = 0; kk < 4; ++kk) {
        bf16x8 af = *(const bf16x8*)(&AT[wave * 16 + lrow][kk * 32 + quad * 8]);
#pragma unroll
        for (int t = 0; t < 8; ++t) {
            bf16x8 bfv = *(const bf16x8*)(Wp + ((t * 4 + kk) * 64 + lane) * 8);
            acc[t] = __builtin_amdgcn_mfma_f32_16x16x32_bf16(af, bfv, acc[t], 0, 0, 0);
        }
    }
    const int r0 = ebase + wave * 16 + quad * 4;
    int eid[4], sv[4], dv[4];
#pragma unroll
    for (int reg = 0; reg < 4; ++reg) {
        eid[reg] = csr[r0 + reg];
        sv[reg] = src[eid[reg]];
        dv[reg] = dstv[eid[reg]];
    }
#pragma unroll
    for (int t = 0; t < 8; ++t) {
        int col = t * 16 + lrow;
        float cbv = cb[col], gv = g[col], btv = bt[col];
        float np = 0.f, dp = 0.f;
        int cur = dv[0];
#pragma unroll
        for (int reg = 0; reg < 4; ++reg) {
            int s = sv[reg], d = dv[reg];
            float Dh = lin[2 * NH + (size_t)s * H + col];
            float Eh = lin[3 * NH + (size_t)d * H + col];
            float e2 = acc[t][reg] + cbv + Dh + Eh;
            float sg = sigf(e2);
            float Bhv = lin[1 * NH + (size_t)s * H + col];
            if (d != cur) {   // flush segment (rows sorted by dst)
                atomicAdd(numden + (size_t)cur * 256 + col * 2,     np);
                atomicAdd(numden + (size_t)cur * 256 + col * 2 + 1, dp);
                np = 0.f; dp = 0.f; cur = d;
            }
            np = fmaf(sg, Bhv, np);
            dp += sg;
            // edge feature output (in-place; each edge row owned by one tile)
            float tt = lrelu(fmaf(gv, e2 * BN_S, btv));
            size_t eoff = (size_t)eid[reg] * H + col;
            float ein = ebuf[eoff];          // fp32 residual, L1/L2-hot
            ebuf[eoff] = lrelu(tt + ein);
        }
        atomicAdd(numden + (size_t)cur * 256 + col * 2,     np);
        atomicAdd(numden + (size_t)cur * 256 + col * 2 + 1, dp);
    }
}

// ---------------- MFMA edge MLP -------------------------------------------
__global__ __launch_bounds__(256) void k_mlp(
        const float* __restrict__ h, const float* __restrict__ ebuf,
        const int* __restrict__ src, const int* __restrict__ dst,
        const unsigned short* __restrict__ w1p,
        const float* __restrict__ b1,
        const float* __restrict__ w2, const float* __restrict__ b2,
        float* __restrict__ out) {
    __shared__ __align__(16) unsigned short AT[64][136];
    const int tid = threadIdx.x;
    const int ebase = blockIdx.x * 64;
    const int lane = tid & 63, wave = tid >> 6;
    const int lrow = lane & 15, quad = lane >> 4;
    f32x4 acc[8] = {};
    for (int chunk = 0; chunk < 3; ++chunk) {
#pragma unroll
        for (int rep = 0; rep < 8; ++rep) {
            int flat = (rep * 256 + tid) * 4;
            int r = flat >> 7, k0 = flat & 127;
            int e = ebase + r;
            const float* base = chunk == 0 ? h + (size_t)src[e] * H
                              : chunk == 1 ? h + (size_t)dst[e] * H
                                           : ebuf + (size_t)e * H;
            float4 v = *(const float4*)(base + k0);
            ushort4 u = { f2b(v.x), f2b(v.y), f2b(v.z), f2b(v.w) };
            *(ushort4*)(&AT[r][k0]) = u;
        }
        __syncthreads();
        const unsigned short* Wp = w1p + (size_t)chunk * 16384;
#pragma unroll
        for (int kk = 0; kk < 4; ++kk) {
            bf16x8 af = *(const bf16x8*)(&AT[wave * 16 + lrow][kk * 32 + quad * 8]);
#pragma unroll
            for (int t = 0; t < 8; ++t) {
                bf16x8 bfv = *(const bf16x8*)(Wp + ((t * 4 + kk) * 64 + lane) * 8);
                acc[t] = __builtin_amdgcn_mfma_f32_16x16x32_bf16(af, bfv, acc[t], 0, 0, 0);
            }
        }
        __syncthreads();
    }
    const float b20 = b2[0], b21 = b2[1];
#pragma unroll
    for (int reg = 0; reg < 4; ++reg) {
        float p0 = 0.f, p1 = 0.f;
#pragma unroll
        for (int t = 0; t < 8; ++t) {
            int col = t * 16 + lrow;
            float hv = fmaxf(acc[t][reg] + b1[col], 0.f);
            p0 = fmaf(hv, w2[col * 2], p0);
            p1 = fmaf(hv, w2[col * 2 + 1], p1);
        }
#pragma unroll
        for (int off = 8; off; off >>= 1) {
            p0 += __shfl_xor(p0, off, 16);
            p1 += __shfl_xor(p1, off, 16);
        }
        if (lrow == 0) {
            int e = ebase + wave * 16 + quad * 4 + reg;
            out[e * 2]     = p0 + b20;
            out[e * 2 + 1] = p1 + b21;
        }
    }
}

extern "C" void kernel_launch(void* const* d_in, const int* in_sizes, int n_in,
                              void* d_out, int out_size, void* d_ws, size_t ws_size,
                              hipStream_t stream) {
    const float* nf  = (const float*)d_in[0];
    const float* ef  = (const float*)d_in[1];
    const int*   src = (const int*)d_in[2];
    const int*   dst = (const int*)d_in[3];
    const float *a0w = (const float*)d_in[4],  *a0b = (const float*)d_in[5];
    const float *b0w = (const float*)d_in[6],  *b0b = (const float*)d_in[7];
    const float *c0w = (const float*)d_in[8],  *c0b = (const float*)d_in[9];
    const float *d0w = (const float*)d_in[10], *d0b = (const float*)d_in[11];
    const float *e0w = (const float*)d_in[12], *e0b = (const float*)d_in[13];
    const float *bnh0g = (const float*)d_in[14], *bnh0b = (const float*)d_in[15];
    const float *bne0g = (const float*)d_in[16], *bne0b = (const float*)d_in[17];
    const float *aLw = (const float*)d_in[18], *aLb = (const float*)d_in[19];
    const float *bLw = (const float*)d_in[20], *bLb = (const float*)d_in[21];
    const float *cLw = (const float*)d_in[22], *cLb = (const float*)d_in[23];
    const float *dLw = (const float*)d_in[24], *dLb = (const float*)d_in[25];
    const float *eLw = (const float*)d_in[26], *eLb = (const float*)d_in[27];
    const float *bnhLg = (const float*)d_in[28], *bnhLb = (const float*)d_in[29];
    const float *bneLg = (const float*)d_in[30], *bneLb = (const float*)d_in[31];
    const float *w1 = (const float*)d_in[32], *b1 = (const float*)d_in[33];
    const float *w2 = (const float*)d_in[34], *b2 = (const float*)d_in[35];
    float* out = (float*)d_out;

    // ws layout (247.7 MB total — must stay under ~256 MB, round-3 lesson):
    // ebuf[NE*H] | lin[4*NH] | numden[NN*256] | h0[NH] | h1[NH] | ints | wpack
    float* ws     = (float*)d_ws;
    float* ebuf   = ws;
    float* lin    = ebuf + (size_t)NE * H;
    float* numden = lin + 4ull * NH;
    float* h0     = numden + (size_t)NN * 256;
    float* h1     = h0 + NH;
    int*   deg    = (int*)(h1 + NH);
    int*   off    = deg + NN;
    int*   cursor = off + NN;
    int*   csr    = cursor + NN;
    unsigned short* wpack = (unsigned short*)(csr + NE);

    // pack weights (13 matrices of 128x128 -> MFMA B-frag order)
    PackPtrs pp;
    const size_t HH = (size_t)H * H;
    for (int l = 0; l < 2; ++l) {
        pp.w[l * 5 + 0] = aLw + l * HH;
        pp.w[l * 5 + 1] = bLw + l * HH;
        pp.w[l * 5 + 2] = dLw + l * HH;
        pp.w[l * 5 + 3] = eLw + l * HH;
        pp.w[l * 5 + 4] = cLw + l * HH;
    }
    pp.w[10] = w1; pp.w[11] = w1 + HH; pp.w[12] = w1 + 2 * HH;
    k_pack<<<104, 256, 0, stream>>>(pp, wpack);

    // CSR build (in-edges, grouped by dst)
    hipMemsetAsync(deg, 0, NN * sizeof(int), stream);
    k_deg<<<(NE + 255) / 256, 256, 0, stream>>>(dst, deg);
    k_scan<<<1, 256, 0, stream>>>(deg, off, cursor);
    k_fill<<<(NE + 255) / 256, 256, 0, stream>>>(dst, cursor, csr);

    // ---- layer 0 ----
    k_nodelin0<<<NN * H / 256, 256, 0, stream>>>(nf, a0w, a0b, b0w, b0b, d0w, d0b, e0w, e0b, lin);
    k_edge0<<<NE / 8, 256, 0, stream>>>(ef, c0w, c0b, src, dst, lin, bne0g, bne0b, ebuf);
    k_agg0<<<NN / 2, 256, 0, stream>>>(csr, off, deg, src, ef, c0w, c0b,
                                       lin, bnh0g, bnh0b, h0);

    // ---- layers 1..2 ----
    for (int l = 0; l < 2; ++l) {
        const float* hin = (l == 0) ? h0 : h1;
        float* hout      = (l == 0) ? h1 : h0;
        k_nodegemm<<<dim3(313, 4), 256, 0, stream>>>(hin,
            wpack + (size_t)l * 5 * 16384,
            aLb + l * H, bLb + l * H, dLb + l * H, eLb + l * H, lin);
        hipMemsetAsync(numden, 0, (size_t)NN * 256 * sizeof(float), stream);
        k_edgegemm<<<NE / 64, 256, 0, stream>>>(ebuf,
                                                wpack + (size_t)(l * 5 + 4) * 16384,
                                                cLb + l * H, src, dst, csr, lin, numden,
                                                bneLg + l * H, bneLb + l * H);
        k_nodeupd<<<NN * 32 / 256, 256, 0, stream>>>(lin, numden,
                                                     bnhLg + l * H, bnhLb + l * H,
                                                     hin, hout);
    }

    // ---- edge classifier MLP ---- (final h is h0)
    k_mlp<<<NE / 64, 256, 0, stream>>>(h0, ebuf, src, dst, wpack + 10ull * 16384,
                                       b1, w2, b2, out);

    (void)in_sizes; (void)n_in; (void)out_size; (void)ws_size;
}